// Round 3
// baseline (82.363 us; speedup 1.0000x reference)
//
#include <hip/hip_runtime.h>

#define BB 4
#define NN 1024
#define MM 1024
#define DD 64
#define TN 128
#define TM 128
#define PAD 68  // 272 B row stride: 16B-aligned, 4-bank skew per row -> conflict-free reads

// 8x8 micro-tile per thread, 128x128 tile per 256-thread block.
// Per dq-quad: 16 ds_read_b128 feed 256 abs-sub-add pairs (512 VALU instr)
// -> per CU: 768 LDS-pipe cyc vs 1024 VALU cyc -> VALU-bound (6.8 us floor).
// 2-stage register pipeline hides LDS latency at 1 wave/SIMD occupancy.

#define COMPUTE(s)                                            \
    _Pragma("unroll")                                         \
    for (int i = 0; i < 8; ++i) {                             \
        _Pragma("unroll")                                     \
        for (int j = 0; j < 8; ++j) {                         \
            acc[i][j] += fabsf(l[s][i].x - r[s][j].x);        \
            acc[i][j] += fabsf(l[s][i].y - r[s][j].y);        \
            acc[i][j] += fabsf(l[s][i].z - r[s][j].z);        \
            acc[i][j] += fabsf(l[s][i].w - r[s][j].w);        \
        }                                                     \
    }

__global__ __launch_bounds__(256, 1)
void SADSimilarity_38706245272206_kernel(const float* __restrict__ lhs,
                                         const float* __restrict__ rhs,
                                         float* __restrict__ out) {
    __shared__ float lt[TN * PAD];
    __shared__ float rt[TM * PAD];

    const int b  = blockIdx.z;
    const int n0 = blockIdx.y * TN;
    const int m0 = blockIdx.x * TM;
    const int tid = threadIdx.x;

    const float* lbase = lhs + ((size_t)b * NN + n0) * DD;
    const float* rbase = rhs + ((size_t)b * MM + m0) * DD;

    // Stage 128 rows x 64 d per tensor: 8 float4-pairs per thread, coalesced.
    #pragma unroll
    for (int p = 0; p < 8; ++p) {
        int e   = tid + p * 256;
        int row = e >> 4;
        int q   = (e & 15) << 2;
        float4 lv = *(const float4*)(lbase + row * DD + q);
        float4 rv = *(const float4*)(rbase + row * DD + q);
        *(float4*)(&lt[row * PAD + q]) = lv;
        *(float4*)(&rt[row * PAD + q]) = rv;
    }
    __syncthreads();

    const int tx = tid & 15;   // cols tx + 16*j
    const int ty = tid >> 4;   // rows ty + 16*i

    float acc[8][8];
    #pragma unroll
    for (int i = 0; i < 8; ++i)
        #pragma unroll
        for (int j = 0; j < 8; ++j) acc[i][j] = 0.0f;

    float4 l[2][8], r[2][8];

    // Prologue: stage 0 loads (dq = 0).
    #pragma unroll
    for (int i = 0; i < 8; ++i) l[0][i] = *(const float4*)(&lt[(ty + 16 * i) * PAD]);
    #pragma unroll
    for (int j = 0; j < 8; ++j) r[0][j] = *(const float4*)(&rt[(tx + 16 * j) * PAD]);

    // Main loop: 2 dq-quads per iteration, double-buffered in registers.
    for (int dq = 0; dq < DD / 4; dq += 2) {
        const int o1 = (dq + 1) * 4;         // always valid (< 64)
        const int o2 = ((dq + 2) & 15) * 4;  // wraps to 0 on last iter (result unused)

        #pragma unroll
        for (int i = 0; i < 8; ++i) l[1][i] = *(const float4*)(&lt[(ty + 16 * i) * PAD + o1]);
        #pragma unroll
        for (int j = 0; j < 8; ++j) r[1][j] = *(const float4*)(&rt[(tx + 16 * j) * PAD + o1]);

        COMPUTE(0)

        #pragma unroll
        for (int i = 0; i < 8; ++i) l[0][i] = *(const float4*)(&lt[(ty + 16 * i) * PAD + o2]);
        #pragma unroll
        for (int j = 0; j < 8; ++j) r[0][j] = *(const float4*)(&rt[(tx + 16 * j) * PAD + o2]);

        COMPUTE(1)
    }

    float* obase = out + ((size_t)b * NN + n0) * MM + m0;
    #pragma unroll
    for (int i = 0; i < 8; ++i) {
        float* orow = obase + (size_t)(ty + 16 * i) * MM;
        #pragma unroll
        for (int j = 0; j < 8; ++j) {
            orow[tx + 16 * j] = -acc[i][j];
        }
    }
}

extern "C" void kernel_launch(void* const* d_in, const int* in_sizes, int n_in,
                              void* d_out, int out_size, void* d_ws, size_t ws_size,
                              hipStream_t stream) {
    const float* lhs = (const float*)d_in[0];
    const float* rhs = (const float*)d_in[1];
    float* out = (float*)d_out;

    dim3 grid(MM / TM, NN / TN, BB);
    dim3 block(256, 1, 1);
    SADSimilarity_38706245272206_kernel<<<grid, block, 0, stream>>>(lhs, rhs, out);
}

// Round 4
// 75.592 us; speedup vs baseline: 1.0896x; 1.0896x over previous
//
#include <hip/hip_runtime.h>

typedef _Float16 h2 __attribute__((ext_vector_type(2)));
typedef _Float16 h4 __attribute__((ext_vector_type(4)));

#define BB 4
#define NN 1024
#define MM 1024
#define DD 64
#define TN 128   // n-rows per block (lhs)
#define TM 64    // m-cols per block (rhs)
#define LROW 72  // f16 row stride: 144 B = 16B-aligned, 4-bank skew per row

static __device__ __forceinline__ h2 toh2(unsigned u) {
    return __builtin_bit_cast(h2, u);
}
static __device__ __forceinline__ h2 hab(h2 x) {
    unsigned u = __builtin_bit_cast(unsigned, x) & 0x7fff7fffu;  // packed |.|: one v_and_b32
    return __builtin_bit_cast(h2, u);
}

// Per 2 elements: pk_sub + and + pk_add = 1.5 VALU instr/elem -> 5.1 us floor.
// b128 LDS read = 8 d-values -> 96 ds_read_b128/thread -> 3.8 us LDS pipe.
// 2 blocks/CU (27 KB LDS, ~180 VGPR) -> 2 waves/SIMD hides latency.
#define COMPUTE(s)                                                     \
    _Pragma("unroll")                                                  \
    for (int i = 0; i < 8; ++i) {                                      \
        _Pragma("unroll")                                              \
        for (int j = 0; j < 4; ++j) {                                  \
            acc[i][j] += hab(toh2(lf[s][i].x) - toh2(rf[s][j].x));     \
            acc[i][j] += hab(toh2(lf[s][i].y) - toh2(rf[s][j].y));     \
            acc[i][j] += hab(toh2(lf[s][i].z) - toh2(rf[s][j].z));     \
            acc[i][j] += hab(toh2(lf[s][i].w) - toh2(rf[s][j].w));     \
        }                                                              \
    }

__global__ __launch_bounds__(256, 2)
void SADSimilarity_38706245272206_kernel(const float* __restrict__ lhs,
                                         const float* __restrict__ rhs,
                                         float* __restrict__ out) {
    __shared__ _Float16 lt[TN * LROW];
    __shared__ _Float16 rt[TM * LROW];

    const int b   = blockIdx.z;
    const int n0  = blockIdx.y * TN;
    const int m0  = blockIdx.x * TM;
    const int tid = threadIdx.x;

    const float* lbase = lhs + ((size_t)b * NN + n0) * DD;
    const float* rbase = rhs + ((size_t)b * MM + m0) * DD;

    // Stage lhs tile: 128 rows x 64 d, fp32 -> f16. 2048 float4 chunks.
    #pragma unroll
    for (int p = 0; p < 8; ++p) {
        int c = tid + p * 256;
        int row = c >> 4, q = c & 15;
        float4 v = *(const float4*)(lbase + row * DD + q * 4);
        h4 w = {(_Float16)v.x, (_Float16)v.y, (_Float16)v.z, (_Float16)v.w};
        *(h4*)(&lt[row * LROW + q * 4]) = w;  // ds_write_b64
    }
    // Stage rhs tile: 64 rows x 64 d. 1024 float4 chunks.
    #pragma unroll
    for (int p = 0; p < 4; ++p) {
        int c = tid + p * 256;
        int row = c >> 4, q = c & 15;
        float4 v = *(const float4*)(rbase + row * DD + q * 4);
        h4 w = {(_Float16)v.x, (_Float16)v.y, (_Float16)v.z, (_Float16)v.w};
        *(h4*)(&rt[row * LROW + q * 4]) = w;
    }
    __syncthreads();

    const int tx = tid & 15;   // m-cols tx + 16*j (j<4)
    const int ty = tid >> 4;   // n-rows ty + 16*i (i<8)

    h2 acc[8][4];
    #pragma unroll
    for (int i = 0; i < 8; ++i)
        #pragma unroll
        for (int j = 0; j < 4; ++j) acc[i][j] = (h2)0;

    // 8 chunks of 8 d-values (16 B each), register double-buffered.
    uint4 lf[2][8], rf[2][4];
    #pragma unroll
    for (int i = 0; i < 8; ++i) lf[0][i] = *(const uint4*)(&lt[(ty + 16 * i) * LROW]);
    #pragma unroll
    for (int j = 0; j < 4; ++j) rf[0][j] = *(const uint4*)(&rt[(tx + 16 * j) * LROW]);

    for (int c = 0; c < 8; c += 2) {
        const int o1 = (c + 1) * 8;        // always < 64
        const int o2 = ((c + 2) & 7) * 8;  // wraps on last iter (unused result)

        #pragma unroll
        for (int i = 0; i < 8; ++i) lf[1][i] = *(const uint4*)(&lt[(ty + 16 * i) * LROW + o1]);
        #pragma unroll
        for (int j = 0; j < 4; ++j) rf[1][j] = *(const uint4*)(&rt[(tx + 16 * j) * LROW + o1]);

        COMPUTE(0)

        #pragma unroll
        for (int i = 0; i < 8; ++i) lf[0][i] = *(const uint4*)(&lt[(ty + 16 * i) * LROW + o2]);
        #pragma unroll
        for (int j = 0; j < 4; ++j) rf[0][j] = *(const uint4*)(&rt[(tx + 16 * j) * LROW + o2]);

        COMPUTE(1)
    }

    float* obase = out + ((size_t)b * NN + n0) * MM + m0;
    #pragma unroll
    for (int i = 0; i < 8; ++i) {
        float* orow = obase + (size_t)(ty + 16 * i) * MM;
        #pragma unroll
        for (int j = 0; j < 4; ++j) {
            h2 a = acc[i][j];
            orow[tx + 16 * j] = -((float)a.x + (float)a.y);
        }
    }
}

extern "C" void kernel_launch(void* const* d_in, const int* in_sizes, int n_in,
                              void* d_out, int out_size, void* d_ws, size_t ws_size,
                              hipStream_t stream) {
    const float* lhs = (const float*)d_in[0];
    const float* rhs = (const float*)d_in[1];
    float* out = (float*)d_out;

    dim3 grid(MM / TM, NN / TN, BB);   // (16, 8, 4) = 512 blocks -> 2 blocks/CU
    dim3 block(256, 1, 1);
    SADSimilarity_38706245272206_kernel<<<grid, block, 0, stream>>>(lhs, rhs, out);
}

// Round 5
// 73.906 us; speedup vs baseline: 1.1144x; 1.0228x over previous
//
#include <hip/hip_runtime.h>

typedef _Float16 h2 __attribute__((ext_vector_type(2)));
typedef _Float16 h4 __attribute__((ext_vector_type(4)));

#define BB 4
#define NN 1024
#define MM 1024
#define DD 64
#define TILE 64
#define LROW 72  // f16 row stride: 144 B = 16B-aligned; r-reads 2-way bank alias (free)

static __device__ __forceinline__ h2 toh2(unsigned u) {
    return __builtin_bit_cast(h2, u);
}
static __device__ __forceinline__ h2 hab(h2 x) {
    unsigned u = __builtin_bit_cast(unsigned, x) & 0x7fff7fffu;  // packed |.|
    return __builtin_bit_cast(h2, u);
}

// Per 8-d chunk: 8 ds_read_b128 feed 192 packed VALU instr -> per CU per round
// LDS 1536 cyc == VALU 1536 cyc, both floor at 5.1 us. 4 blocks/CU (r1's
// occupancy, the empirical winner) hides the lgkmcnt gaps.
#define COMPUTE(s)                                                 \
    _Pragma("unroll")                                              \
    for (int i = 0; i < 4; ++i) {                                  \
        _Pragma("unroll")                                          \
        for (int j = 0; j < 4; ++j) {                              \
            acc[i][j] += hab(toh2(lf[s][i].x) - toh2(rf[s][j].x)); \
            acc[i][j] += hab(toh2(lf[s][i].y) - toh2(rf[s][j].y)); \
            acc[i][j] += hab(toh2(lf[s][i].z) - toh2(rf[s][j].z)); \
            acc[i][j] += hab(toh2(lf[s][i].w) - toh2(rf[s][j].w)); \
        }                                                          \
    }

__global__ __launch_bounds__(256, 4)
void SADSimilarity_38706245272206_kernel(const float* __restrict__ lhs,
                                         const float* __restrict__ rhs,
                                         float* __restrict__ out) {
    __shared__ _Float16 lt[TILE * LROW];
    __shared__ _Float16 rt[TILE * LROW];

    const int b   = blockIdx.z;
    const int n0  = blockIdx.y * TILE;
    const int m0  = blockIdx.x * TILE;
    const int tid = threadIdx.x;

    const float* lbase = lhs + ((size_t)b * NN + n0) * DD;
    const float* rbase = rhs + ((size_t)b * MM + m0) * DD;

    // Stage both 64x64 tiles, fp32 -> f16 (RTE via scalar casts; cost ~1%).
    #pragma unroll
    for (int p = 0; p < 4; ++p) {
        int c = tid + p * 256;
        int row = c >> 4, q = (c & 15) * 4;
        float4 lv = *(const float4*)(lbase + row * DD + q);
        float4 rv = *(const float4*)(rbase + row * DD + q);
        h4 lw = {(_Float16)lv.x, (_Float16)lv.y, (_Float16)lv.z, (_Float16)lv.w};
        h4 rw = {(_Float16)rv.x, (_Float16)rv.y, (_Float16)rv.z, (_Float16)rv.w};
        *(h4*)(&lt[row * LROW + q]) = lw;  // ds_write_b64, conflict-free
        *(h4*)(&rt[row * LROW + q]) = rw;
    }
    __syncthreads();

    const int tx = tid & 15;   // cols tx + 16*j
    const int ty = tid >> 4;   // rows ty + 16*i

    h2 acc[4][4];
    #pragma unroll
    for (int i = 0; i < 4; ++i)
        #pragma unroll
        for (int j = 0; j < 4; ++j) acc[i][j] = (h2)0;

    // 8 chunks of 8 d-values (16 B), register double-buffered.
    uint4 lf[2][4], rf[2][4];
    #pragma unroll
    for (int i = 0; i < 4; ++i) lf[0][i] = *(const uint4*)(&lt[(ty + 16 * i) * LROW]);
    #pragma unroll
    for (int j = 0; j < 4; ++j) rf[0][j] = *(const uint4*)(&rt[(tx + 16 * j) * LROW]);

    for (int c = 0; c < 8; c += 2) {
        const int o1 = (c + 1) * 8;        // h-offset, always < 64
        const int o2 = ((c + 2) & 7) * 8;  // wraps on last iter (result unused)

        #pragma unroll
        for (int i = 0; i < 4; ++i) lf[1][i] = *(const uint4*)(&lt[(ty + 16 * i) * LROW + o1]);
        #pragma unroll
        for (int j = 0; j < 4; ++j) rf[1][j] = *(const uint4*)(&rt[(tx + 16 * j) * LROW + o1]);

        COMPUTE(0)

        #pragma unroll
        for (int i = 0; i < 4; ++i) lf[0][i] = *(const uint4*)(&lt[(ty + 16 * i) * LROW + o2]);
        #pragma unroll
        for (int j = 0; j < 4; ++j) rf[0][j] = *(const uint4*)(&rt[(tx + 16 * j) * LROW + o2]);

        COMPUTE(1)
    }

    float* obase = out + ((size_t)b * NN + n0) * MM + m0;
    #pragma unroll
    for (int i = 0; i < 4; ++i) {
        float* orow = obase + (size_t)(ty + 16 * i) * MM;
        #pragma unroll
        for (int j = 0; j < 4; ++j) {
            h2 a = acc[i][j];
            orow[tx + 16 * j] = -((float)a.x + (float)a.y);
        }
    }
}

extern "C" void kernel_launch(void* const* d_in, const int* in_sizes, int n_in,
                              void* d_out, int out_size, void* d_ws, size_t ws_size,
                              hipStream_t stream) {
    const float* lhs = (const float*)d_in[0];
    const float* rhs = (const float*)d_in[1];
    float* out = (float*)d_out;

    dim3 grid(MM / TILE, NN / TILE, BB);  // (16,16,4) = 1024 blocks -> 4 blocks/CU
    dim3 block(256, 1, 1);
    SADSimilarity_38706245272206_kernel<<<grid, block, 0, stream>>>(lhs, rhs, out);
}